// Round 8
// baseline (659.687 us; speedup 1.0000x reference)
//
#include <hip/hip_runtime.h>
#include <hip/hip_bf16.h>
#include <stdint.h>

// LPLRQuantizedLinear: B=8192 rows, N=M=4096, rank 64 (48 frozen + 16 ft).
// ALL float tensors are FP32 (per reference); Q_idxs int32; output FP32.
//
// Pipeline:
//   prep     : R_cat[64][4096] bf16 (ws), L_cat -> Wq[:, 4096:4160] bf16
//   decode   : Wq[:, :4096] = bf16(0.02 * grid[Q_idxs])      (f32 grid)
//   fwht_pre : h[:, :4096] = bf16(FWHT(x*SU)/64)             (radix-16 3-pass)
//   tgemm    : Tpart = h @ R_cat^T (k-split 4, fp32 partials)
//   tconv    : h[:, 4096:4160] = bf16(sum Tpart)
//   mgemm    : d_out = f32( h[8192,4160] @ Wq[4096,4160]^T ) -- v8 read-ahead
//   fwht_post: d_out = (FWHT(d_out)/64) * SV                 (radix-16 3-pass)
//
// mgemm history (measured):
//   v2b ring4 2ph: 283  | v3 1bar: 350 | v4 4ph/2K: 334 | v5 hoist: 287
//   v6 ring2 2blk/CU: 2438 (acc spill) | v7 BK64 m201-ish: 280, MfmaUtil 43%
// Common flaw of all ~280 variants: each phase reads ITS OWN operands
// (reads -> bar -> MFMA) so the matrix pipe idles during every LDS drain.
// v8: software-pipelined operand reads -- ph1(t) reads ALL 12 fragments of
// tile t+1 (legal: vmcnt(6)@ph0(t) retires t+1, bar makes it collective)
// into ping/pong register sets, consumed at ph0(t+1) via compiler counted
// lgkmcnt (drain hides under MFMA). 2 barriers/K-step (was 4). Offset regs
// collapsed: XOR mask ((fr>>1)&3)<<4 is frag-invariant -> base + imm offs.
// VGPR ledger ~110 + 128 acc(AGPR) = ~238 < 256 (no spill; v6 lesson).

typedef __bf16 bf16;
typedef __bf16 bf16x8 __attribute__((ext_vector_type(8)));
typedef float f32x4 __attribute__((ext_vector_type(4)));

#define KE 4160
#define NN 4096
#define MM 4096
#define BB 8192

// ---------------- prep: build R_cat (bf16) and L columns of Wq ----------------
__global__ void prep_kernel(const float* __restrict__ Lft, const float* __restrict__ Rft,
                            const float* __restrict__ Lres, const float* __restrict__ Rres,
                            bf16* __restrict__ Rcat, bf16* __restrict__ Wq) {
  int tid = blockIdx.x * 256 + threadIdx.x;   // 524288 total
  if (tid < 64 * 4096) {
    int r = tid >> 12, n = tid & 4095;
    float v = (r < 48) ? Rres[r * 4096 + n] : Rft[(r - 48) * 4096 + n];
    Rcat[tid] = (bf16)v;
  } else {
    int t2 = tid - 64 * 4096;
    int m = t2 >> 6, r = t2 & 63;
    float v = (r < 48) ? Lres[m * 48 + r] : Lft[m * 16 + (r - 48)];
    Wq[(size_t)m * KE + 4096 + r] = (bf16)v;
  }
}

// ---------------- decode: Wq[:, :4096] = bf16(0.02*grid[Q_idxs]) ----------------
__global__ void decode_kernel(const int* __restrict__ qidx, const float* __restrict__ grid,
                              bf16* __restrict__ Wq) {
  int tid = blockIdx.x * 256 + threadIdx.x;   // 4096*512 = 2M
  int m = tid >> 9, g = tid & 511;
  uint32_t idx = (uint32_t)qidx[tid];
  const float4* gp = (const float4*)(grid + (size_t)idx * 8);
  float4 w0 = gp[0], w1 = gp[1];
  bf16x8 o;
  o[0] = (bf16)(w0.x * 0.02f); o[1] = (bf16)(w0.y * 0.02f);
  o[2] = (bf16)(w0.z * 0.02f); o[3] = (bf16)(w0.w * 0.02f);
  o[4] = (bf16)(w1.x * 0.02f); o[5] = (bf16)(w1.y * 0.02f);
  o[6] = (bf16)(w1.z * 0.02f); o[7] = (bf16)(w1.w * 0.02f);
  *(bf16x8*)(Wq + (size_t)m * KE + g * 8) = o;
}

// 4-stage (16-point) FWHT on a register array
#define FWHT16(v) \
  _Pragma("unroll") \
  for (int s_ = 1; s_ < 16; s_ <<= 1) { \
    _Pragma("unroll") \
    for (int i_ = 0; i_ < 16; ++i_) { \
      if (!(i_ & s_)) { float a_ = v[i_], b_ = v[i_ + s_]; v[i_] = a_ + b_; v[i_ + s_] = a_ - b_; } \
    } \
  }

// ---------------- FWHT-4096 radix-16 3-pass, f32 in -> bf16 out ----------------
__global__ void fwht_pre_kernel(const float* __restrict__ src,
                                bf16* __restrict__ dst,
                                const float* __restrict__ SU) {
  __shared__ float buf[4352];
  const int row = blockIdx.x, t = threadIdx.x;
  const float4* sp = (const float4*)(src + (size_t)row * NN + t * 16);
  const float4* su = (const float4*)(SU + t * 16);
  float v[16];
#pragma unroll
  for (int q = 0; q < 4; ++q) {
    float4 a = sp[q], s = su[q];
    v[q * 4 + 0] = a.x * s.x; v[q * 4 + 1] = a.y * s.y;
    v[q * 4 + 2] = a.z * s.z; v[q * 4 + 3] = a.w * s.w;
  }
  FWHT16(v)
#pragma unroll
  for (int i = 0; i < 16; ++i) buf[17 * t + i] = v[i];
  __syncthreads();
  const int base = ((t >> 4) << 8) | (t & 15);
#pragma unroll
  for (int k = 0; k < 16; ++k) { int a = base + (k << 4); v[k] = buf[a + (a >> 4)]; }
  FWHT16(v)
#pragma unroll
  for (int k = 0; k < 16; ++k) { int a = base + (k << 4); buf[a + (a >> 4)] = v[k]; }
  __syncthreads();
#pragma unroll
  for (int k = 0; k < 16; ++k) { int a = t + (k << 8); v[k] = buf[a + (a >> 4)]; }
  FWHT16(v)
  bf16* dp = dst + (size_t)row * KE;
#pragma unroll
  for (int k = 0; k < 16; ++k) dp[t + (k << 8)] = (bf16)(v[k] * 0.015625f);
}

// ---------------- FWHT-4096 radix-16 3-pass, f32 in-place (post, *SV) ----------------
__global__ void fwht_post_kernel(float* __restrict__ data, const float* __restrict__ SV) {
  __shared__ float buf[4352];
  const int row = blockIdx.x, t = threadIdx.x;
  const float4* dp = (const float4*)(data + (size_t)row * MM + t * 16);
  float v[16];
#pragma unroll
  for (int q = 0; q < 4; ++q) {
    float4 a = dp[q];
    v[q * 4 + 0] = a.x; v[q * 4 + 1] = a.y; v[q * 4 + 2] = a.z; v[q * 4 + 3] = a.w;
  }
  FWHT16(v)
#pragma unroll
  for (int i = 0; i < 16; ++i) buf[17 * t + i] = v[i];
  __syncthreads();
  const int base = ((t >> 4) << 8) | (t & 15);
#pragma unroll
  for (int k = 0; k < 16; ++k) { int a = base + (k << 4); v[k] = buf[a + (a >> 4)]; }
  FWHT16(v)
#pragma unroll
  for (int k = 0; k < 16; ++k) { int a = base + (k << 4); buf[a + (a >> 4)] = v[k]; }
  __syncthreads();
#pragma unroll
  for (int k = 0; k < 16; ++k) { int a = t + (k << 8); v[k] = buf[a + (a >> 4)]; }
  FWHT16(v)
  float* op = data + (size_t)row * MM;
#pragma unroll
  for (int k = 0; k < 16; ++k) { int a = t + (k << 8); op[a] = v[k] * 0.015625f * SV[a]; }
}

// ---------------- tgemm: Tpart[split] = h @ R_cat^T ----------------
__global__ void __launch_bounds__(256) tgemm_kernel(const bf16* __restrict__ A,
                                                    const bf16* __restrict__ Bm,
                                                    float* __restrict__ Tpart) {
  __shared__ bf16 lA[128 * 32];
  __shared__ bf16 lB[64 * 32];
  const int t = threadIdx.x, w = t >> 6, l = t & 63;
  const int bmBlk = blockIdx.x;
  const int split = blockIdx.y;
  const int wm = w >> 1, wn = w & 1;
  f32x4 acc[4][2] = {};
  const int arow = t >> 1, acol = (t & 1) * 16;
  const bf16* pa = A + (size_t)(bmBlk * 128 + arow) * KE + acol;
  const int brow = (t & 127) >> 1, bcol = acol;
  const bf16* pb = Bm + (size_t)brow * 4096 + bcol;
  const int fr = l & 15, fk = (l >> 4) * 8;
  for (int kt = 0; kt < 32; ++kt) {
    const int k0 = (split * 32 + kt) * 32;
    bf16x8 a0 = *(const bf16x8*)(pa + k0);
    bf16x8 a1 = *(const bf16x8*)(pa + k0 + 8);
    *(bf16x8*)&lA[arow * 32 + acol] = a0;
    *(bf16x8*)&lA[arow * 32 + acol + 8] = a1;
    if (t < 128) {
      bf16x8 b0 = *(const bf16x8*)(pb + k0);
      bf16x8 b1 = *(const bf16x8*)(pb + k0 + 8);
      *(bf16x8*)&lB[brow * 32 + bcol] = b0;
      *(bf16x8*)&lB[brow * 32 + bcol + 8] = b1;
    }
    __syncthreads();
    bf16x8 af[4], bfr[2];
#pragma unroll
    for (int i = 0; i < 4; ++i) af[i] = *(const bf16x8*)&lA[(wm * 64 + i * 16 + fr) * 32 + fk];
#pragma unroll
    for (int i = 0; i < 2; ++i) bfr[i] = *(const bf16x8*)&lB[(wn * 32 + i * 16 + fr) * 32 + fk];
#pragma unroll
    for (int mi = 0; mi < 4; ++mi)
#pragma unroll
      for (int ni = 0; ni < 2; ++ni)
        acc[mi][ni] = __builtin_amdgcn_mfma_f32_16x16x32_bf16(af[mi], bfr[ni], acc[mi][ni], 0, 0, 0);
    __syncthreads();
  }
  float* out = Tpart + (size_t)split * BB * 64;
  const int orow = bmBlk * 128 + wm * 64 + (l >> 4) * 4;
  const int ocol = wn * 32 + (l & 15);
#pragma unroll
  for (int mi = 0; mi < 4; ++mi)
#pragma unroll
    for (int ni = 0; ni < 2; ++ni)
#pragma unroll
      for (int r = 0; r < 4; ++r)
        out[(size_t)(orow + mi * 16 + r) * 64 + ocol + ni * 16] = acc[mi][ni][r];
}

__global__ void tconv_kernel(const float* __restrict__ Tpart, bf16* __restrict__ h) {
  int i = blockIdx.x * 256 + threadIdx.x;
  float s = Tpart[i] + Tpart[i + BB * 64] + Tpart[i + 2 * BB * 64] + Tpart[i + 3 * BB * 64];
  int row = i >> 6, c = i & 63;
  h[(size_t)row * KE + 4096 + c] = (bf16)s;
}

// ---------------- mgemm v8: 256^2, ring-4, read-ahead pipeline, 2 bars/K-step ----------------
// Per K-step t (slot t&3):
//  ph0(t): stage A(t+3); vmcnt(6) [retires tile t+1]; MFMA A(t) x B-lo(t); bar
//  ph1(t): stage B(t+3); ds_read ALL 12 frags of tile t+1 (ping/pong regs);
//          MFMA A(t) x B-hi(t); bar
// Tile t+1 is collectively landed at ph1(t) (every wave's vmcnt(6) + bar).
// Its reads drain under ph1's MFMA + ph0(t+1)'s counted lgkmcnt.
// Stage-safety: slot (t+3)&3 = (t-1)&3; A(t-1)/B(t-1) reads (ph1(t-2)) were
// consumed by ph0/ph1(t-1) MFMAs (lgkm-drained) >=1 barrier before staging.
// vmcnt ledger: at ph0(t) after STAGE_A(t+3): newest 6 outstanding =
// {A(t+3),B(t+2),A(t+2)} -> retired through B(t+1). Tails: t=127 vmcnt(4),
// t=128 vmcnt(0), t=129 none (no tile-130 reads).

__device__ __forceinline__ void gload16(const void* g, void* l) {
  __builtin_amdgcn_global_load_lds(
      (const __attribute__((address_space(1))) void*)g,
      (__attribute__((address_space(3))) void*)l, 16, 0, 0);
}

__device__ __forceinline__ void bar() {
  asm volatile("" ::: "memory");
  __builtin_amdgcn_s_barrier();
  asm volatile("" ::: "memory");
}

#define VM(n) { asm volatile("s_waitcnt vmcnt(" #n ")" ::: "memory"); __builtin_amdgcn_sched_barrier(0); }

// stage tile s (A or B): 2 gloads; chunk1 source = +16 rows (=133120 B), dst = +1024
#define STAGE_A(s) { const char* g_ = gA0 + (size_t)(s) * 64; \
  char* d_ = &sA[(((s) & 3) << 14) + dA0]; \
  gload16(g_, d_); gload16(g_ + 133120, d_ + 1024); }
#define STAGE_B(s) { const char* g_ = gB0 + (size_t)(s) * 64; \
  char* d_ = &sB[(((s) & 3) << 14) + dA0]; \
  gload16(g_, d_); gload16(g_ + 133120, d_ + 1024); }

// read all 12 fragments of tile s into register set (Ax[8], Blx[2], Bhx[2])
#define RDTILE(s, Ax, Blx, Bhx) { \
  const int sb_ = ((s) & 3) << 14; \
  const char* pa_ = &sA[sb_ + offA0]; \
  const char* pb_ = &sB[sb_ + offB0]; \
  _Pragma("unroll") \
  for (int m_ = 0; m_ < 8; ++m_) Ax[m_] = *(const bf16x8*)(pa_ + m_ * 1024); \
  Blx[0] = *(const bf16x8*)(pb_);        Blx[1] = *(const bf16x8*)(pb_ + 1024); \
  Bhx[0] = *(const bf16x8*)(pb_ + 2048); Bhx[1] = *(const bf16x8*)(pb_ + 3072); }

// 16 MFMA: acc[m][nb], acc[m][nb+1]
#define MF16(Ax, Bx, nb) \
  __builtin_amdgcn_s_setprio(1); \
  _Pragma("unroll") \
  for (int m_ = 0; m_ < 8; ++m_) { \
    acc[m_][(nb)]     = __builtin_amdgcn_mfma_f32_16x16x32_bf16(Ax[m_], Bx[0], acc[m_][(nb)], 0, 0, 0); \
    acc[m_][(nb) + 1] = __builtin_amdgcn_mfma_f32_16x16x32_bf16(Ax[m_], Bx[1], acc[m_][(nb) + 1], 0, 0, 0); \
  } \
  __builtin_amdgcn_s_setprio(0);

__global__ void __launch_bounds__(512, 2) mgemm_kernel(const bf16* __restrict__ A,
                                                       const bf16* __restrict__ B,
                                                       float* __restrict__ C) {
  __shared__ alignas(16) char sA[65536];   // 4 slots x 256x32 bf16
  __shared__ alignas(16) char sB[65536];
  const int t = threadIdx.x;
  const int w = t >> 6, l = t & 63;
  const int wm = w >> 2, wn = w & 3;           // 2M x 4N waves, per-wave 128x64
  // bijective XCD swizzle (512 blocks, 512%8==0)
  const int bid = blockIdx.x;
  const int swzb = (bid & 7) * 64 + (bid >> 3);
  const int bm = swzb >> 4, bn = swzb & 15;

  // staging: chunk c0 = w*2 covers LDS [c0*1024, +1024); chunk c0+1 via +const.
  // Source col pre-swizzled (involution) so linear LDS + swizzled reads agree.
  const int c0 = w * 2;
  const int lb0 = c0 * 1024 + l * 16;
  const int sb0 = lb0 ^ (((lb0 >> 7) & 3) << 4);
  const char* gA0 = (const char*)A + (size_t)(bm * 256 + (sb0 >> 6)) * (KE * 2) + (sb0 & 63);
  const char* gB0 = (const char*)B + (size_t)(bn * 256 + (sb0 >> 6)) * (KE * 2) + (sb0 & 63);
  const int dA0 = c0 * 1024;

  // fragment bases: XOR mask ((fr>>1)&3)<<4 is mi/ni-invariant (bits 7-8 of
  // the byte addr come from fr only) -> 2 base offsets + imm 1024*frag.
  const int fr = l & 15;
  const int colA = ((l >> 4) << 4) ^ (((fr >> 1) & 3) << 4);
  const int offA0 = (wm * 128 + fr) * 64 + colA;
  const int offB0 = (wn * 64 + fr) * 64 + colA;

  f32x4 acc[8][4] = {};
  bf16x8 Ae[8], Ao[8], Ble[2], Bhe[2], Blo[2], Bho[2];

  // prologue: stage tiles 0,1,2 (A,B interleaved); vmcnt(8) -> tile 0 landed
  STAGE_A(0) STAGE_B(0) STAGE_A(1) STAGE_B(1) STAGE_A(2) STAGE_B(2)
  VM(8)
  bar();
  RDTILE(0, Ae, Ble, Bhe)

  for (int j = 0; j < 65; ++j) {
    const int t0 = 2 * j, t1 = 2 * j + 1;
    // ---- ph0(t0)  [t0 even: 0..128]
    if (t0 <= 126) STAGE_A(t0 + 3)
    if (t0 <= 126) { VM(6) } else if (t0 == 128) { VM(0) }
    MF16(Ae, Ble, 0)
    bar();
    // ---- ph1(t0): read-ahead tile t0+1 (always <= 129)
    if (t0 <= 126) STAGE_B(t0 + 3)
    RDTILE(t0 + 1, Ao, Blo, Bho)
    MF16(Ae, Bhe, 2)
    bar();
    // ---- ph0(t1)  [t1 odd: 1..129]
    if (t1 <= 126) STAGE_A(t1 + 3)
    if (t1 <= 126) { VM(6) } else if (t1 == 127) { VM(4) }
    MF16(Ao, Blo, 0)
    bar();
    // ---- ph1(t1): read-ahead tile t1+1, except t1==129
    if (t1 <= 126) STAGE_B(t1 + 3)
    if (t1 <= 128) RDTILE(t1 + 1, Ae, Ble, Bhe)
    MF16(Ao, Bho, 2)
    bar();
  }

  // epilogue: C write (verified lane->C mapping)
  const int orow = bm * 256 + wm * 128 + ((l >> 4) << 2);
  const int ocol = bn * 256 + wn * 64 + (l & 15);
#pragma unroll
  for (int mi = 0; mi < 8; ++mi)
#pragma unroll
    for (int ni = 0; ni < 4; ++ni)
#pragma unroll
      for (int r = 0; r < 4; ++r)
        C[(size_t)(orow + mi * 16 + r) * MM + ocol + ni * 16] = acc[mi][ni][r];
}

extern "C" void kernel_launch(void* const* d_in, const int* in_sizes, int n_in,
                              void* d_out, int out_size, void* d_ws, size_t ws_size,
                              hipStream_t stream) {
  const float* x    = (const float*)d_in[0];
  const float* SU   = (const float*)d_in[1];
  const float* SV   = (const float*)d_in[2];
  const float* grid = (const float*)d_in[3];
  const float* Lft  = (const float*)d_in[4];
  const float* Rft  = (const float*)d_in[5];
  const float* Lres = (const float*)d_in[6];
  const float* Rres = (const float*)d_in[7];
  const int*   qidx = (const int*)d_in[10];
  float* out = (float*)d_out;

  char* ws = (char*)d_ws;
  bf16*  h     = (bf16*)ws;                                   // 8192*4160*2 = 68,157,440
  bf16*  Wq    = (bf16*)(ws + 68157440);                      // 4096*4160*2 = 34,078,720
  bf16*  Rcat  = (bf16*)(ws + 68157440 + 34078720);           // 64*4096*2   =    524,288
  float* Tpart = (float*)(ws + 68157440 + 34078720 + 524288); // 4*8192*64*4 =  8,388,608

  prep_kernel<<<2048, 256, 0, stream>>>(Lft, Rft, Lres, Rres, Rcat, Wq);
  decode_kernel<<<8192, 256, 0, stream>>>(qidx, grid, Wq);
  fwht_pre_kernel<<<8192, 256, 0, stream>>>(x, h, SU);
  tgemm_kernel<<<dim3(64, 4), 256, 0, stream>>>(h, Rcat, Tpart);
  tconv_kernel<<<2048, 256, 0, stream>>>(Tpart, h);
  mgemm_kernel<<<512, 512, 0, stream>>>(h, Wq, out);
  fwht_post_kernel<<<8192, 256, 0, stream>>>(out, SV);
}